// Round 3
// baseline (31807.526 us; speedup 1.0000x reference)
//
#include <hip/hip_runtime.h>
#include <hip/hip_cooperative_groups.h>

namespace cg = cooperative_groups;

#define NBATCH 32
#define NPTS   100000
#define NDIM   6
#define KSEL   1024
#define BPB    8                  // blocks per batch
#define NTHREADS 1024
#define TOTT   (BPB * NTHREADS)   // 8192 threads per batch
#define PPT    13                 // ceil(NPTS / TOTT)

struct Slots {
    double d[2][NBATCH][BPB];     // per-block best distance (parity double-buffered)
    int    idx[2][NBATCH][BPB];   // per-block best index
};

__global__ void __launch_bounds__(NTHREADS, 1) fps_main(const float* __restrict__ pts,
                                                        float* __restrict__ out,
                                                        Slots* __restrict__ sl)
{
#pragma clang fp contract(off)
    cg::grid_group grid = cg::this_grid();

    const int bid   = blockIdx.x;
    const int batch = bid >> 3;             // 8 consecutive blocks per batch
    const int blk   = bid & 7;              // 0..7 within batch
    const int tid   = threadIdx.x;
    const int lane  = tid & 63;
    const int wav   = tid >> 6;             // 0..15
    const int tg    = blk * NTHREADS + tid; // 0..8191 within batch

    __shared__ double rd[16];
    __shared__ int    ri[16];
    __shared__ int    idx_l[KSEL];          // used by blk==0 only
    __shared__ double fr0[16], fr1[16], fr2[16];
    __shared__ double sc[4];

    const float* base = pts + (size_t)batch * NPTS * NDIM;

    // ---- load point state: xyz in f32 registers (exact when widened), dist state in f64
    float  px[PPT], py[PPT], pz[PPT];
    double pd[PPT];
#pragma unroll
    for (int k = 0; k < PPT; ++k) {
        int gi = k * TOTT + tg;
        if (gi < NPTS) {
            const float* p = base + (size_t)gi * NDIM;
            px[k] = p[0]; py[k] = p[1]; pz[k] = p[2];
            pd[k] = 1e10;
        } else {
            px[k] = 0.f; py[k] = 0.f; pz[k] = 0.f;
            pd[k] = -1.0;   // never wins argmax (valid dists >= 0)
        }
    }

    double lx = (double)base[0], ly = (double)base[1], lz = (double)base[2]; // first = index 0

    for (int t = 0; t < KSEL - 1; ++t) {
        // ---- f64 distance update + thread-local argmax (order-matched to numpy: (xx+yy)+zz)
        double bd = -1.0; int bi = 0x7FFFFFFF;
#pragma unroll
        for (int k = 0; k < PPT; ++k) {
            double dx = (double)px[k] - lx;
            double dy = (double)py[k] - ly;
            double dz = (double)pz[k] - lz;
            double dd = ((dx * dx) + (dy * dy)) + (dz * dz);
            double nd = fmin(pd[k], dd);
            pd[k] = nd;
            if (nd > bd) { bd = nd; bi = k * TOTT + tg; }  // strict >: first max in-thread
        }
        // ---- wave reduce: (dist desc, idx asc)
#pragma unroll
        for (int off = 32; off >= 1; off >>= 1) {
            double od = __shfl_xor(bd, off, 64);
            int    oi = __shfl_xor(bi, off, 64);
            if (od > bd || (od == bd && oi < bi)) { bd = od; bi = oi; }
        }
        if (lane == 0) { rd[wav] = bd; ri[wav] = bi; }
        __syncthreads();
        // ---- block reduce (wave 0) -> per-block slot
        if (wav == 0) {
            double qd = (lane < 16) ? rd[lane] : -2.0;
            int    qi = (lane < 16) ? ri[lane] : 0x7FFFFFFF;
#pragma unroll
            for (int off = 8; off >= 1; off >>= 1) {
                double od = __shfl_xor(qd, off, 64);
                int    oi = __shfl_xor(qi, off, 64);
                if (od > qd || (od == qd && oi < qi)) { qd = od; qi = oi; }
            }
            if (lane == 0) {
                sl->d[t & 1][batch][blk]   = qd;
                sl->idx[t & 1][batch][blk] = qi;
            }
        }
        // ---- grid-wide barrier; parity double-buffer prevents overwrite races
        grid.sync();
        // ---- every thread reduces the 8 slots deterministically
        double wd = sl->d[t & 1][batch][0];
        int    wi = sl->idx[t & 1][batch][0];
#pragma unroll
        for (int b = 1; b < BPB; ++b) {
            double od = sl->d[t & 1][batch][b];
            int    oi = sl->idx[t & 1][batch][b];
            if (od > wd || (od == wd && oi < wi)) { wd = od; wi = oi; }
        }
        if (blk == 0 && tid == 0) idx_l[t + 1] = wi;
        const float* lp = base + (size_t)wi * NDIM;
        lx = (double)lp[0]; ly = (double)lp[1]; lz = (double)lp[2];
    }

    if (blk != 0) return;

    // ============ epilogue (block 0 of each batch): gather + normalize, f64 accumulation ============
    if (tid == 0) idx_l[0] = 0;
    __syncthreads();

    int si = idx_l[tid];
    const float* sp = base + (size_t)si * NDIM;
    float sx = sp[0], sy = sp[1], szv = sp[2];
    float f3 = sp[3], f4 = sp[4], f5 = sp[5];

    // centroid = mean over K of xyz (f64 accumulate)
    double rx = (double)sx, ry = (double)sy, rz = (double)szv;
#pragma unroll
    for (int off = 32; off >= 1; off >>= 1) {
        rx += __shfl_xor(rx, off, 64);
        ry += __shfl_xor(ry, off, 64);
        rz += __shfl_xor(rz, off, 64);
    }
    if (lane == 0) { fr0[wav] = rx; fr1[wav] = ry; fr2[wav] = rz; }
    __syncthreads();
    if (tid == 0) {
        double tx = 0., ty = 0., tz = 0.;
        for (int i = 0; i < 16; ++i) { tx += fr0[i]; ty += fr1[i]; tz += fr2[i]; }
        sc[0] = tx / (double)KSEL; sc[1] = ty / (double)KSEL; sc[2] = tz / (double)KSEL;
    }
    __syncthreads();
    double ax = (double)sx - sc[0], ay = (double)sy - sc[1], az = (double)szv - sc[2];
    double m = fmax(fabs(ax), fmax(fabs(ay), fabs(az)));
#pragma unroll
    for (int off = 32; off >= 1; off >>= 1) {
        double om = __shfl_xor(m, off, 64);
        m = fmax(m, om);
    }
    if (lane == 0) fr0[wav] = m;
    __syncthreads();
    if (tid == 0) {
        double mm = 0.;
        for (int i = 0; i < 16; ++i) mm = fmax(mm, fr0[i]);
        sc[3] = fmax(mm, 1e-6);
    }
    __syncthreads();
    double scale = sc[3];

    float* ob = out + ((size_t)batch * KSEL + tid) * NDIM;
    ob[0] = (float)(ax / scale);
    ob[1] = (float)(ay / scale);
    ob[2] = (float)(az / scale);
    ob[3] = f3; ob[4] = f4; ob[5] = f5;
}

extern "C" void kernel_launch(void* const* d_in, const int* in_sizes, int n_in,
                              void* d_out, int out_size, void* d_ws, size_t ws_size,
                              hipStream_t stream)
{
    const float* pts = (const float*)d_in[0];
    float* out = (float*)d_out;
    Slots* sl = (Slots*)d_ws;

    void* args[] = { (void*)&pts, (void*)&out, (void*)&sl };
    hipLaunchCooperativeKernel((void*)fps_main, dim3(NBATCH * BPB), dim3(NTHREADS),
                               args, 0, stream);
}